// Round 13
// baseline (347.611 us; speedup 1.0000x reference)
//
#include <hip/hip_runtime.h>

#define DF 128
constexpr int NN = 40000;
constexpr int EE = 20000;
constexpr int MM = 640000;
constexpr float EPSF = 1e-5f;
constexpr float ALPHA = 0.1f;
constexpr int SE = 96;   // slots/edge, 192B = 3 cache lines
constexpr int SV = 64;   // slots/vertex, 128B = 2 cache lines

// fusedA: [G double-gemm | A2 gemm | e-side build]
constexpr int NB_G1 = (NN + 63) / 64;            // 625
constexpr int NB_G2 = (NN + 63) / 64;            // 625
constexpr int NB_GEMMS = NB_G1 + NB_G2;          // 1250
constexpr int NB_EBUILD = 5000;                  // 625 groups x 8 roles, 4 chunks
// fusedB: [gather1B | v-side build]
constexpr int NB_GB1 = EE / 4;                   // 5000
constexpr int NB_VBUILD = 5000;

// role-contiguous counter layout: lines of cnt are XCD-exclusive
__device__ __forceinline__ int cidxE(int e) { return (e & 7) * (EE >> 3) + (e >> 3); }
__device__ __forceinline__ int cidxV(int v) { return (v & 7) * (NN >> 3) + (v >> 3); }

typedef float f32x4 __attribute__((ext_vector_type(4)));
__device__ __forceinline__ void nt_store4(float* p, float a, float b, float c, float d) {
  f32x4 v = {a, b, c, d};
  __builtin_nontemporal_store(v, (f32x4*)p);
}

// ---------------------------------------------------------------------------
// prek: zero cnt arrays (60000 ints) + combo Wc = w1_2@w2_1_bot, bc = b1_2@w2_1_bot
__global__ __launch_bounds__(256) void prek(int* __restrict__ cnt,
                                            const float* __restrict__ w1_2,
                                            const float* __restrict__ b1_2,
                                            const float* __restrict__ w2_1,
                                            float* __restrict__ Wc,
                                            float* __restrict__ bc) {
  int b = blockIdx.x;
  if (b < 235) {
    int i = b * 256 + threadIdx.x;
    if (i < 60000) cnt[i] = 0;
  } else {
    const float* w2b = w2_1 + 128 * DF;
    int out = (b - 235) * 256 + threadIdx.x;
    if (out < 16384) {
      int i = out >> 7;
      int j = out & 127;
      float s = 0.0f;
      for (int k = 0; k < 128; ++k) s += w1_2[i * DF + k] * w2b[k * DF + j];
      Wc[out] = s;
    } else if (out < 16512) {
      int j = out - 16384;
      float s = 0.0f;
      for (int k = 0; k < 128; ++k) s += b1_2[k] * w2b[k * DF + j];
      bc[j] = s;
    }
  }
}

// ---------------------------------------------------------------------------
// gemm tile body (single): C = epi(A@W + bias); EPI 0 none, EPI 2 residual-mix.
//   STATS: per-row sum/sumsq out. C written nontemporal (streaming).
template <int EPI, bool STATS>
__device__ __forceinline__ void gemm_tile(const float* __restrict__ A, int nrows,
                                          const float* __restrict__ W,
                                          const float* __restrict__ bias,
                                          const int* __restrict__ cnt,
                                          const float* __restrict__ xres,
                                          float* __restrict__ C,
                                          float* __restrict__ sOut,
                                          float* __restrict__ qOut,
                                          int blk, float* as) {
  int tid = threadIdx.x;
  int rbase = blk * 64;

  #pragma unroll
  for (int j = 0; j < 8; ++j) {
    int q = tid + j * 256;
    int row = q >> 5;
    int c4 = q & 31;
    int grow = rbase + row;
    float4 v = make_float4(0.f, 0.f, 0.f, 0.f);
    if (grow < nrows) {
      v = *reinterpret_cast<const float4*>(A + (size_t)grow * DF + c4 * 4);
    }
    *reinterpret_cast<float4*>(&as[row * 132 + c4 * 4]) = v;
  }
  __syncthreads();

  int tc = tid & 15;
  int tr = tid >> 4;
  int cbase = tc * 8;

  float acc[4][8];
  #pragma unroll
  for (int i = 0; i < 4; ++i)
    #pragma unroll
    for (int c = 0; c < 8; ++c) acc[i][c] = 0.0f;

  #pragma unroll 4
  for (int k = 0; k < 128; ++k) {
    float w[8];
    *reinterpret_cast<float4*>(&w[0]) = *reinterpret_cast<const float4*>(W + k * DF + cbase);
    *reinterpret_cast<float4*>(&w[4]) = *reinterpret_cast<const float4*>(W + k * DF + cbase + 4);
    float a[4];
    #pragma unroll
    for (int i = 0; i < 4; ++i) a[i] = as[(tr * 4 + i) * 132 + k];
    #pragma unroll
    for (int i = 0; i < 4; ++i)
      #pragma unroll
      for (int c = 0; c < 8; ++c) acc[i][c] += a[i] * w[c];
  }

  if (bias) {
    #pragma unroll
    for (int i = 0; i < 4; ++i)
      #pragma unroll
      for (int c = 0; c < 8; ++c) acc[i][c] += bias[cbase + c];
  }

  if (STATS) {
    #pragma unroll
    for (int i = 0; i < 4; ++i) {
      float s = 0.f, q = 0.f;
      #pragma unroll
      for (int c = 0; c < 8; ++c) { s += acc[i][c]; q += acc[i][c] * acc[i][c]; }
      #pragma unroll
      for (int mask = 1; mask <= 8; mask <<= 1) {
        s += __shfl_xor(s, mask, 16);
        q += __shfl_xor(q, mask, 16);
      }
      if (tc == 0) {
        int grow = rbase + tr * 4 + i;
        if (grow < nrows) { sOut[grow] = s; qOut[grow] = q; }
      }
    }
  }

  #pragma unroll
  for (int i = 0; i < 4; ++i) {
    int grow = rbase + tr * 4 + i;
    if (grow >= nrows) continue;
    float outv[8];
    if (EPI == 2) {
      int cv = cnt[(grow & 7) * (NN >> 3) + (grow >> 3)];  // role-remapped cnt_v
      #pragma unroll
      for (int c = 0; c < 8; ++c) {
        float xv = xres[(size_t)grow * DF + cbase + c];
        outv[c] = (cv == 0) ? ALPHA * xv : (1.0f - ALPHA) * acc[i][c] + ALPHA * xv;
      }
    } else {
      #pragma unroll
      for (int c = 0; c < 8; ++c) outv[c] = acc[i][c];
    }
    nt_store4(C + (size_t)grow * DF + cbase, outv[0], outv[1], outv[2], outv[3]);
    nt_store4(C + (size_t)grow * DF + cbase + 4, outv[4], outv[5], outv[6], outv[7]);
  }
}

// ---------------------------------------------------------------------------
// double gemm tile: G = relu(LN(x@W1 + b1; g, be)) @ W2  (bias folded later).
__device__ __forceinline__ void gemm_tile_double(const float* __restrict__ x,
                                                 const float* __restrict__ W1,
                                                 const float* __restrict__ b1,
                                                 const float* __restrict__ g,
                                                 const float* __restrict__ be,
                                                 const float* __restrict__ W2,
                                                 float* __restrict__ G,
                                                 int blk, float* as) {
  int tid = threadIdx.x;
  int rbase = blk * 64;

  #pragma unroll
  for (int j = 0; j < 8; ++j) {
    int q = tid + j * 256;
    int row = q >> 5;
    int c4 = q & 31;
    int grow = rbase + row;
    float4 v = make_float4(0.f, 0.f, 0.f, 0.f);
    if (grow < NN) {
      v = *reinterpret_cast<const float4*>(x + (size_t)grow * DF + c4 * 4);
    }
    *reinterpret_cast<float4*>(&as[row * 132 + c4 * 4]) = v;
  }
  __syncthreads();

  int tc = tid & 15;
  int tr = tid >> 4;
  int cbase = tc * 8;

  float acc[4][8];
  #pragma unroll
  for (int i = 0; i < 4; ++i)
    #pragma unroll
    for (int c = 0; c < 8; ++c) acc[i][c] = 0.0f;

  #pragma unroll 4
  for (int k = 0; k < 128; ++k) {
    float w[8];
    *reinterpret_cast<float4*>(&w[0]) = *reinterpret_cast<const float4*>(W1 + k * DF + cbase);
    *reinterpret_cast<float4*>(&w[4]) = *reinterpret_cast<const float4*>(W1 + k * DF + cbase + 4);
    float a[4];
    #pragma unroll
    for (int i = 0; i < 4; ++i) a[i] = as[(tr * 4 + i) * 132 + k];
    #pragma unroll
    for (int i = 0; i < 4; ++i)
      #pragma unroll
      for (int c = 0; c < 8; ++c) acc[i][c] += a[i] * w[c];
  }

  // bias + LN + relu -> t
  float gv[8], bev[8];
  #pragma unroll
  for (int c = 0; c < 8; ++c) { gv[c] = g[cbase + c]; bev[c] = be[cbase + c]; }
  #pragma unroll
  for (int i = 0; i < 4; ++i) {
    #pragma unroll
    for (int c = 0; c < 8; ++c) acc[i][c] += b1[cbase + c];
    float s = 0.f, s2 = 0.f;
    #pragma unroll
    for (int c = 0; c < 8; ++c) { s += acc[i][c]; s2 += acc[i][c] * acc[i][c]; }
    #pragma unroll
    for (int mask = 1; mask <= 8; mask <<= 1) {
      s += __shfl_xor(s, mask, 16);
      s2 += __shfl_xor(s2, mask, 16);
    }
    float mean = s * (1.0f / 128.0f);
    float var = s2 * (1.0f / 128.0f) - mean * mean;
    float rs = rsqrtf(var + EPSF);
    #pragma unroll
    for (int c = 0; c < 8; ++c) {
      float y = (acc[i][c] - mean) * rs * gv[c] + bev[c];
      acc[i][c] = fmaxf(y, 0.0f);
    }
  }

  // stage t into LDS (after all stage-1 reads complete)
  __syncthreads();
  #pragma unroll
  for (int i = 0; i < 4; ++i)
    #pragma unroll
    for (int c = 0; c < 8; ++c) as[(tr * 4 + i) * 132 + cbase + c] = acc[i][c];
  __syncthreads();

  // stage 2: G = t @ W2
  #pragma unroll
  for (int i = 0; i < 4; ++i)
    #pragma unroll
    for (int c = 0; c < 8; ++c) acc[i][c] = 0.0f;

  #pragma unroll 4
  for (int k = 0; k < 128; ++k) {
    float w[8];
    *reinterpret_cast<float4*>(&w[0]) = *reinterpret_cast<const float4*>(W2 + k * DF + cbase);
    *reinterpret_cast<float4*>(&w[4]) = *reinterpret_cast<const float4*>(W2 + k * DF + cbase + 4);
    float a[4];
    #pragma unroll
    for (int i = 0; i < 4; ++i) a[i] = as[(tr * 4 + i) * 132 + k];
    #pragma unroll
    for (int i = 0; i < 4; ++i)
      #pragma unroll
      for (int c = 0; c < 8; ++c) acc[i][c] += a[i] * w[c];
  }

  #pragma unroll
  for (int i = 0; i < 4; ++i) {
    int grow = rbase + tr * 4 + i;
    if (grow >= NN) continue;
    nt_store4(G + (size_t)grow * DF + cbase, acc[i][0], acc[i][1], acc[i][2], acc[i][3]);
    nt_store4(G + (size_t)grow * DF + cbase + 4, acc[i][4], acc[i][5], acc[i][6], acc[i][7]);
  }
}

// ---------------------------------------------------------------------------
// fusedA: [G double-gemm | A2 gemm | e-side XCD-partitioned build]
__global__ __launch_bounds__(256) void fusedA(
    const int* __restrict__ ei,
    int* __restrict__ cnt_e, ushort* __restrict__ lst_e,
    const float* __restrict__ x,
    const float* __restrict__ w1_1, const float* __restrict__ b1_1,
    const float* __restrict__ g1, const float* __restrict__ be1,
    const float* __restrict__ w2_1, const float* __restrict__ Wc,
    float* __restrict__ G, float* __restrict__ A2,
    float* __restrict__ sA, float* __restrict__ qA) {
  __shared__ float as[64 * 132];
  int blk = blockIdx.x;
  if (blk < NB_G1) {
    gemm_tile_double(x, w1_1, b1_1, g1, be1, Wc, G, blk, as);
  } else if (blk < NB_GEMMS) {
    gemm_tile<0, true>(x, NN, w2_1, nullptr, nullptr, nullptr, A2, sA, qA,
                       blk - NB_G1, as);
  } else {
    int b = blk - NB_GEMMS;
    int role = blk & 7;
    int group = b >> 3;
    #pragma unroll
    for (int k = 0; k < 4; ++k) {
      int m = (group * 4 + k) * 256 + threadIdx.x;
      int v = __builtin_nontemporal_load(ei + m);
      int e = __builtin_nontemporal_load(ei + MM + m);
      if ((e & 7) == role) {
        int pe = atomicAdd(&cnt_e[role * (EE >> 3) + (e >> 3)], 1);
        lst_e[e * SE + pe] = (ushort)v;
      }
    }
  }
}

// ---------------------------------------------------------------------------
// fusedB: [gather1B | v-side XCD-partitioned build]
// gather1B: B[e] = mean_{v in e} G[v] + bc + b2_1, plus row stats sB,qB.
__global__ __launch_bounds__(256) void fusedB(
    const float* __restrict__ G,
    const int* __restrict__ cnt_e, const ushort* __restrict__ lst_e,
    const float* __restrict__ bcv, const float* __restrict__ b21,
    float* __restrict__ B, float* __restrict__ sB, float* __restrict__ qB,
    const int* __restrict__ ei,
    int* __restrict__ cnt_v, ushort* __restrict__ lst_v) {
  int blk = blockIdx.x;
  if (blk < NB_GB1) {
    int e = blk * 4 + (threadIdx.x >> 6);
    int lane = threadIdx.x & 63;
    int g = lane >> 4;
    int l = lane & 15;
    int deg = cnt_e[cidxE(e)];
    const ushort* lst = lst_e + e * SE;
    float4 acc0 = make_float4(0.f, 0.f, 0.f, 0.f);
    float4 acc1 = make_float4(0.f, 0.f, 0.f, 0.f);
    for (int i = g; i < deg; i += 4) {
      int v = lst[i];
      const float* src = G + (size_t)v * DF + l * 8;
      float4 h0 = *reinterpret_cast<const float4*>(src);
      float4 h1 = *reinterpret_cast<const float4*>(src + 4);
      acc0.x += h0.x; acc0.y += h0.y; acc0.z += h0.z; acc0.w += h0.w;
      acc1.x += h1.x; acc1.y += h1.y; acc1.z += h1.z; acc1.w += h1.w;
    }
    #pragma unroll
    for (int mask = 16; mask <= 32; mask <<= 1) {
      acc0.x += __shfl_xor(acc0.x, mask); acc0.y += __shfl_xor(acc0.y, mask);
      acc0.z += __shfl_xor(acc0.z, mask); acc0.w += __shfl_xor(acc0.w, mask);
      acc1.x += __shfl_xor(acc1.x, mask); acc1.y += __shfl_xor(acc1.y, mask);
      acc1.z += __shfl_xor(acc1.z, mask); acc1.w += __shfl_xor(acc1.w, mask);
    }
    if (g == 0) {
      float sc = 1.0f / (float)(deg > 1 ? deg : 1);
      float b[8];
      b[0] = acc0.x * sc + bcv[l * 8 + 0] + b21[l * 8 + 0];
      b[1] = acc0.y * sc + bcv[l * 8 + 1] + b21[l * 8 + 1];
      b[2] = acc0.z * sc + bcv[l * 8 + 2] + b21[l * 8 + 2];
      b[3] = acc0.w * sc + bcv[l * 8 + 3] + b21[l * 8 + 3];
      b[4] = acc1.x * sc + bcv[l * 8 + 4] + b21[l * 8 + 4];
      b[5] = acc1.y * sc + bcv[l * 8 + 5] + b21[l * 8 + 5];
      b[6] = acc1.z * sc + bcv[l * 8 + 6] + b21[l * 8 + 6];
      b[7] = acc1.w * sc + bcv[l * 8 + 7] + b21[l * 8 + 7];
      float* dst = B + (size_t)e * DF + l * 8;
      *reinterpret_cast<float4*>(dst) = make_float4(b[0], b[1], b[2], b[3]);
      *reinterpret_cast<float4*>(dst + 4) = make_float4(b[4], b[5], b[6], b[7]);
      float s = 0.f, q = 0.f;
      #pragma unroll
      for (int j = 0; j < 8; ++j) { s += b[j]; q += b[j] * b[j]; }
      #pragma unroll
      for (int mask = 1; mask <= 8; mask <<= 1) {
        s += __shfl_xor(s, mask, 16);
        q += __shfl_xor(q, mask, 16);
      }
      if (l == 0) { sB[e] = s; qB[e] = q; }
    }
  } else {
    int b = blk - NB_GB1;
    int role = blk & 7;   // NB_GB1 = 5000 is divisible by 8 -> role == b&7
    int group = b >> 3;
    #pragma unroll
    for (int k = 0; k < 4; ++k) {
      int m = (group * 4 + k) * 256 + threadIdx.x;
      int v = __builtin_nontemporal_load(ei + m);
      int e = __builtin_nontemporal_load(ei + MM + m);
      if ((v & 7) == role) {
        int pv = atomicAdd(&cnt_v[role * (NN >> 3) + (v >> 3)], 1);
        lst_v[v * SV + pv] = (ushort)e;
      }
    }
  }
}

// ---------------------------------------------------------------------------
// standalone gemm dispatch wrapper (out-gemm)
template <int EPI, bool STATS>
__global__ __launch_bounds__(256) void gemm128(const float* __restrict__ A, int nrows,
                                               const float* __restrict__ W,
                                               const float* __restrict__ bias,
                                               const int* __restrict__ cnt,
                                               const float* __restrict__ xres,
                                               float* __restrict__ C,
                                               float* __restrict__ sOut,
                                               float* __restrict__ qOut) {
  __shared__ float as[64 * 132];
  gemm_tile<EPI, STATS>(A, nrows, W, bias, cnt, xres, C, sOut, qOut,
                        blockIdx.x, as);
}

// ---------------------------------------------------------------------------
// gather2: Svmean[v] = mean_{e in v} relu(LN(A2[v] + B[e]; g2, be2))
// LN split: s = sA[v]+sB[e], q = qA[v]+qB[e]+2*dot(A2[v],B[e]).
__global__ __launch_bounds__(256) void gather2(const float* __restrict__ A2,
                                               const float* __restrict__ B,
                                               const float* __restrict__ sA,
                                               const float* __restrict__ qA,
                                               const float* __restrict__ sB,
                                               const float* __restrict__ qB,
                                               const int* __restrict__ cnt_v,
                                               const ushort* __restrict__ lst_v,
                                               const float* __restrict__ g2,
                                               const float* __restrict__ be2,
                                               float* __restrict__ Svmean) {
  int v = blockIdx.x * 4 + (threadIdx.x >> 6);
  int lane = threadIdx.x & 63;
  int g = lane >> 4;
  int l = lane & 15;
  const float* ap = A2 + (size_t)v * DF + l * 8;
  float4 a0 = *reinterpret_cast<const float4*>(ap);
  float4 a1 = *reinterpret_cast<const float4*>(ap + 4);
  float4 gv0 = *reinterpret_cast<const float4*>(g2 + l * 8);
  float4 gv1 = *reinterpret_cast<const float4*>(g2 + l * 8 + 4);
  float4 bv0 = *reinterpret_cast<const float4*>(be2 + l * 8);
  float4 bv1 = *reinterpret_cast<const float4*>(be2 + l * 8 + 4);
  float sAv = sA[v];
  float qAv = qA[v];
  int deg = cnt_v[cidxV(v)];
  const ushort* lst = lst_v + v * SV;
  float4 acc0 = make_float4(0.f, 0.f, 0.f, 0.f);
  float4 acc1 = make_float4(0.f, 0.f, 0.f, 0.f);
  for (int i = g; i < deg; i += 4) {
    int e = lst[i];
    const float* bp = B + (size_t)e * DF + l * 8;
    float4 b0 = *reinterpret_cast<const float4*>(bp);
    float4 b1 = *reinterpret_cast<const float4*>(bp + 4);
    float d = a0.x * b0.x + a0.y * b0.y + a0.z * b0.z + a0.w * b0.w +
              a1.x * b1.x + a1.y * b1.y + a1.z * b1.z + a1.w * b1.w;
    d += __shfl_xor(d, 1, 16);
    d += __shfl_xor(d, 2, 16);
    d += __shfl_xor(d, 4, 16);
    d += __shfl_xor(d, 8, 16);
    float s = sAv + sB[e];
    float q = qAv + qB[e] + 2.0f * d;
    float mean = s * (1.0f / 128.0f);
    float var = q * (1.0f / 128.0f) - mean * mean;
    float rs = rsqrtf(var + EPSF);
    float mrs = mean * rs;
    float t;
    t = (a0.x + b0.x) * rs - mrs; acc0.x += fmaxf(t * gv0.x + bv0.x, 0.f);
    t = (a0.y + b0.y) * rs - mrs; acc0.y += fmaxf(t * gv0.y + bv0.y, 0.f);
    t = (a0.z + b0.z) * rs - mrs; acc0.z += fmaxf(t * gv0.z + bv0.z, 0.f);
    t = (a0.w + b0.w) * rs - mrs; acc0.w += fmaxf(t * gv0.w + bv0.w, 0.f);
    t = (a1.x + b1.x) * rs - mrs; acc1.x += fmaxf(t * gv1.x + bv1.x, 0.f);
    t = (a1.y + b1.y) * rs - mrs; acc1.y += fmaxf(t * gv1.y + bv1.y, 0.f);
    t = (a1.z + b1.z) * rs - mrs; acc1.z += fmaxf(t * gv1.z + bv1.z, 0.f);
    t = (a1.w + b1.w) * rs - mrs; acc1.w += fmaxf(t * gv1.w + bv1.w, 0.f);
  }
  #pragma unroll
  for (int mask = 16; mask <= 32; mask <<= 1) {
    acc0.x += __shfl_xor(acc0.x, mask); acc0.y += __shfl_xor(acc0.y, mask);
    acc0.z += __shfl_xor(acc0.z, mask); acc0.w += __shfl_xor(acc0.w, mask);
    acc1.x += __shfl_xor(acc1.x, mask); acc1.y += __shfl_xor(acc1.y, mask);
    acc1.z += __shfl_xor(acc1.z, mask); acc1.w += __shfl_xor(acc1.w, mask);
  }
  if (g == 0) {
    float sc = 1.0f / (float)(deg > 1 ? deg : 1);
    float* dst = Svmean + (size_t)v * DF + l * 8;
    *reinterpret_cast<float4*>(dst) =
        make_float4(acc0.x * sc, acc0.y * sc, acc0.z * sc, acc0.w * sc);
    *reinterpret_cast<float4*>(dst + 4) =
        make_float4(acc1.x * sc, acc1.y * sc, acc1.z * sc, acc1.w * sc);
  }
}

// ---------------------------------------------------------------------------
extern "C" void kernel_launch(void* const* d_in, const int* in_sizes, int n_in,
                              void* d_out, int out_size, void* d_ws, size_t ws_size,
                              hipStream_t stream) {
  const float* x    = (const float*)d_in[0];
  const float* w1_1 = (const float*)d_in[1];
  const float* b1_1 = (const float*)d_in[2];
  const float* g1   = (const float*)d_in[3];
  const float* be1  = (const float*)d_in[4];
  const float* w1_2 = (const float*)d_in[5];
  const float* b1_2 = (const float*)d_in[6];
  const float* w2_1 = (const float*)d_in[7];
  const float* b2_1 = (const float*)d_in[8];
  const float* g2   = (const float*)d_in[9];
  const float* be2  = (const float*)d_in[10];
  const float* w2_2 = (const float*)d_in[11];
  const float* b2_2 = (const float*)d_in[12];
  const int* ei     = (const int*)d_in[13];
  float* out = (float*)d_out;

  float* ws = (float*)d_ws;
  float* bufN1 = ws;                    // N*D: G, then Svmean
  float* bufN2 = ws + 5120000;          // N*D: A2
  float* bufE  = ws + 10240000;         // E*D: B
  float* Wc    = ws + 12800000;         // 128*128
  float* bc    = ws + 12816384;         // 128
  float* sA    = ws + 12816512;         // N
  float* qA    = ws + 12856512;         // N
  float* sB    = ws + 12896512;         // E
  float* qB    = ws + 12916512;         // E
  int*   ints  = (int*)(ws + 12936512);
  int* cnt_e  = ints;                   // E  role-remapped (zeroed by prek)
  int* cnt_v  = ints + 20000;           // N  role-remapped (zeroed by prek)
  ushort* lst_e = (ushort*)(ints + 60000);            // EE*SE ushorts
  ushort* lst_v = (ushort*)(ints + 60000 + 960000);   // NN*SV ushorts

  // zero cnt + combo (Wc, bc)
  prek<<<300, 256, 0, stream>>>(cnt_e, w1_2, b1_2, w2_1, Wc, bc);

  // fusedA: G = relu(LN(x@w1_1+b1_1))@Wc || A2 = x@w2_1_top (+stats) || e-build
  fusedA<<<NB_GEMMS + NB_EBUILD, 256, 0, stream>>>(
      ei, cnt_e, lst_e, x, w1_1, b1_1, g1, be1, w2_1, Wc,
      bufN1, bufN2, sA, qA);

  // fusedB: B[e] = mean of G rows + bc + b2_1 (+stats) || v-build
  fusedB<<<NB_GB1 + NB_VBUILD, 256, 0, stream>>>(
      bufN1, cnt_e, lst_e, bc, b2_1, bufE, sB, qB, ei, cnt_v, lst_v);

  // Svmean[v] = mean of relu(LN(A2[v] + B[e]))  (into bufN1; G dead)
  gather2<<<NN / 4, 256, 0, stream>>>(bufN2, bufE, sA, qA, sB, qB,
                                      cnt_v, lst_v, g2, be2, bufN1);

  // out = 0.9*(Svmean@w2_2 + b2_2) + 0.1*x   (cnt_v==0 -> 0.1*x)
  gemm128<2, false><<<(NN + 63) / 64, 256, 0, stream>>>(
      bufN1, NN, w2_2, b2_2, cnt_v, x, out, nullptr, nullptr);
}

// Round 15
// 344.194 us; speedup vs baseline: 1.0099x; 1.0099x over previous
//
#include <hip/hip_runtime.h>

#define DF 128
constexpr int NN = 40000;
constexpr int EE = 20000;
constexpr int MM = 640000;
constexpr float EPSF = 1e-5f;
constexpr float ALPHA = 0.1f;
constexpr int SE = 96;   // slots/edge, 192B = 3 cache lines
constexpr int SV = 64;   // slots/vertex, 128B = 2 cache lines

// fusedA: [G double-gemm | A2 gemm | combined e+v build]
constexpr int NB_G1 = (NN + 63) / 64;            // 625
constexpr int NB_G2 = (NN + 63) / 64;            // 625
constexpr int NB_GEMMS = NB_G1 + NB_G2;          // 1250
constexpr int NB_BUILD = 5000;                   // 625 groups x 8 roles, 4 chunks

// role-contiguous counter layout: lines of cnt are XCD-exclusive
__device__ __forceinline__ int cidxE(int e) { return (e & 7) * (EE >> 3) + (e >> 3); }
__device__ __forceinline__ int cidxV(int v) { return (v & 7) * (NN >> 3) + (v >> 3); }

typedef float f32x4 __attribute__((ext_vector_type(4)));
__device__ __forceinline__ void nt_store4(float* p, float a, float b, float c, float d) {
  f32x4 v = {a, b, c, d};
  __builtin_nontemporal_store(v, (f32x4*)p);
}

// ---------------------------------------------------------------------------
// prek: zero cnt arrays (60000 ints) + combo Wc = w1_2@w2_1_bot, bc = b1_2@w2_1_bot
__global__ __launch_bounds__(256) void prek(int* __restrict__ cnt,
                                            const float* __restrict__ w1_2,
                                            const float* __restrict__ b1_2,
                                            const float* __restrict__ w2_1,
                                            float* __restrict__ Wc,
                                            float* __restrict__ bc) {
  int b = blockIdx.x;
  if (b < 235) {
    int i = b * 256 + threadIdx.x;
    if (i < 60000) cnt[i] = 0;
  } else {
    const float* w2b = w2_1 + 128 * DF;
    int out = (b - 235) * 256 + threadIdx.x;
    if (out < 16384) {
      int i = out >> 7;
      int j = out & 127;
      float s = 0.0f;
      for (int k = 0; k < 128; ++k) s += w1_2[i * DF + k] * w2b[k * DF + j];
      Wc[out] = s;
    } else if (out < 16512) {
      int j = out - 16384;
      float s = 0.0f;
      for (int k = 0; k < 128; ++k) s += b1_2[k] * w2b[k * DF + j];
      bc[j] = s;
    }
  }
}

// ---------------------------------------------------------------------------
// gemm tile body (single): C = epi(A@W + bias); EPI 0 none, EPI 2 residual-mix.
//   STATS: per-row sum/sumsq out. C written nontemporal (streaming).
template <int EPI, bool STATS>
__device__ __forceinline__ void gemm_tile(const float* __restrict__ A, int nrows,
                                          const float* __restrict__ W,
                                          const float* __restrict__ bias,
                                          const int* __restrict__ cnt,
                                          const float* __restrict__ xres,
                                          float* __restrict__ C,
                                          float* __restrict__ sOut,
                                          float* __restrict__ qOut,
                                          int blk, float* as) {
  int tid = threadIdx.x;
  int rbase = blk * 64;

  #pragma unroll
  for (int j = 0; j < 8; ++j) {
    int q = tid + j * 256;
    int row = q >> 5;
    int c4 = q & 31;
    int grow = rbase + row;
    float4 v = make_float4(0.f, 0.f, 0.f, 0.f);
    if (grow < nrows) {
      v = *reinterpret_cast<const float4*>(A + (size_t)grow * DF + c4 * 4);
    }
    *reinterpret_cast<float4*>(&as[row * 132 + c4 * 4]) = v;
  }
  __syncthreads();

  int tc = tid & 15;
  int tr = tid >> 4;
  int cbase = tc * 8;

  float acc[4][8];
  #pragma unroll
  for (int i = 0; i < 4; ++i)
    #pragma unroll
    for (int c = 0; c < 8; ++c) acc[i][c] = 0.0f;

  #pragma unroll 4
  for (int k = 0; k < 128; ++k) {
    float w[8];
    *reinterpret_cast<float4*>(&w[0]) = *reinterpret_cast<const float4*>(W + k * DF + cbase);
    *reinterpret_cast<float4*>(&w[4]) = *reinterpret_cast<const float4*>(W + k * DF + cbase + 4);
    float a[4];
    #pragma unroll
    for (int i = 0; i < 4; ++i) a[i] = as[(tr * 4 + i) * 132 + k];
    #pragma unroll
    for (int i = 0; i < 4; ++i)
      #pragma unroll
      for (int c = 0; c < 8; ++c) acc[i][c] += a[i] * w[c];
  }

  if (bias) {
    #pragma unroll
    for (int i = 0; i < 4; ++i)
      #pragma unroll
      for (int c = 0; c < 8; ++c) acc[i][c] += bias[cbase + c];
  }

  if (STATS) {
    #pragma unroll
    for (int i = 0; i < 4; ++i) {
      float s = 0.f, q = 0.f;
      #pragma unroll
      for (int c = 0; c < 8; ++c) { s += acc[i][c]; q += acc[i][c] * acc[i][c]; }
      #pragma unroll
      for (int mask = 1; mask <= 8; mask <<= 1) {
        s += __shfl_xor(s, mask, 16);
        q += __shfl_xor(q, mask, 16);
      }
      if (tc == 0) {
        int grow = rbase + tr * 4 + i;
        if (grow < nrows) { sOut[grow] = s; qOut[grow] = q; }
      }
    }
  }

  #pragma unroll
  for (int i = 0; i < 4; ++i) {
    int grow = rbase + tr * 4 + i;
    if (grow >= nrows) continue;
    float outv[8];
    if (EPI == 2) {
      int cv = cnt[(grow & 7) * (NN >> 3) + (grow >> 3)];  // role-remapped cnt_v
      #pragma unroll
      for (int c = 0; c < 8; ++c) {
        float xv = xres[(size_t)grow * DF + cbase + c];
        outv[c] = (cv == 0) ? ALPHA * xv : (1.0f - ALPHA) * acc[i][c] + ALPHA * xv;
      }
    } else {
      #pragma unroll
      for (int c = 0; c < 8; ++c) outv[c] = acc[i][c];
    }
    nt_store4(C + (size_t)grow * DF + cbase, outv[0], outv[1], outv[2], outv[3]);
    nt_store4(C + (size_t)grow * DF + cbase + 4, outv[4], outv[5], outv[6], outv[7]);
  }
}

// ---------------------------------------------------------------------------
// double gemm tile: G = relu(LN(x@W1 + b1; g, be)) @ W2  (bias folded later).
__device__ __forceinline__ void gemm_tile_double(const float* __restrict__ x,
                                                 const float* __restrict__ W1,
                                                 const float* __restrict__ b1,
                                                 const float* __restrict__ g,
                                                 const float* __restrict__ be,
                                                 const float* __restrict__ W2,
                                                 float* __restrict__ G,
                                                 int blk, float* as) {
  int tid = threadIdx.x;
  int rbase = blk * 64;

  #pragma unroll
  for (int j = 0; j < 8; ++j) {
    int q = tid + j * 256;
    int row = q >> 5;
    int c4 = q & 31;
    int grow = rbase + row;
    float4 v = make_float4(0.f, 0.f, 0.f, 0.f);
    if (grow < NN) {
      v = *reinterpret_cast<const float4*>(x + (size_t)grow * DF + c4 * 4);
    }
    *reinterpret_cast<float4*>(&as[row * 132 + c4 * 4]) = v;
  }
  __syncthreads();

  int tc = tid & 15;
  int tr = tid >> 4;
  int cbase = tc * 8;

  float acc[4][8];
  #pragma unroll
  for (int i = 0; i < 4; ++i)
    #pragma unroll
    for (int c = 0; c < 8; ++c) acc[i][c] = 0.0f;

  #pragma unroll 4
  for (int k = 0; k < 128; ++k) {
    float w[8];
    *reinterpret_cast<float4*>(&w[0]) = *reinterpret_cast<const float4*>(W1 + k * DF + cbase);
    *reinterpret_cast<float4*>(&w[4]) = *reinterpret_cast<const float4*>(W1 + k * DF + cbase + 4);
    float a[4];
    #pragma unroll
    for (int i = 0; i < 4; ++i) a[i] = as[(tr * 4 + i) * 132 + k];
    #pragma unroll
    for (int i = 0; i < 4; ++i)
      #pragma unroll
      for (int c = 0; c < 8; ++c) acc[i][c] += a[i] * w[c];
  }

  // bias + LN + relu -> t
  float gv[8], bev[8];
  #pragma unroll
  for (int c = 0; c < 8; ++c) { gv[c] = g[cbase + c]; bev[c] = be[cbase + c]; }
  #pragma unroll
  for (int i = 0; i < 4; ++i) {
    #pragma unroll
    for (int c = 0; c < 8; ++c) acc[i][c] += b1[cbase + c];
    float s = 0.f, s2 = 0.f;
    #pragma unroll
    for (int c = 0; c < 8; ++c) { s += acc[i][c]; s2 += acc[i][c] * acc[i][c]; }
    #pragma unroll
    for (int mask = 1; mask <= 8; mask <<= 1) {
      s += __shfl_xor(s, mask, 16);
      s2 += __shfl_xor(s2, mask, 16);
    }
    float mean = s * (1.0f / 128.0f);
    float var = s2 * (1.0f / 128.0f) - mean * mean;
    float rs = rsqrtf(var + EPSF);
    #pragma unroll
    for (int c = 0; c < 8; ++c) {
      float y = (acc[i][c] - mean) * rs * gv[c] + bev[c];
      acc[i][c] = fmaxf(y, 0.0f);
    }
  }

  // stage t into LDS (after all stage-1 reads complete)
  __syncthreads();
  #pragma unroll
  for (int i = 0; i < 4; ++i)
    #pragma unroll
    for (int c = 0; c < 8; ++c) as[(tr * 4 + i) * 132 + cbase + c] = acc[i][c];
  __syncthreads();

  // stage 2: G = t @ W2
  #pragma unroll
  for (int i = 0; i < 4; ++i)
    #pragma unroll
    for (int c = 0; c < 8; ++c) acc[i][c] = 0.0f;

  #pragma unroll 4
  for (int k = 0; k < 128; ++k) {
    float w[8];
    *reinterpret_cast<float4*>(&w[0]) = *reinterpret_cast<const float4*>(W2 + k * DF + cbase);
    *reinterpret_cast<float4*>(&w[4]) = *reinterpret_cast<const float4*>(W2 + k * DF + cbase + 4);
    float a[4];
    #pragma unroll
    for (int i = 0; i < 4; ++i) a[i] = as[(tr * 4 + i) * 132 + k];
    #pragma unroll
    for (int i = 0; i < 4; ++i)
      #pragma unroll
      for (int c = 0; c < 8; ++c) acc[i][c] += a[i] * w[c];
  }

  #pragma unroll
  for (int i = 0; i < 4; ++i) {
    int grow = rbase + tr * 4 + i;
    if (grow >= NN) continue;
    nt_store4(G + (size_t)grow * DF + cbase, acc[i][0], acc[i][1], acc[i][2], acc[i][3]);
    nt_store4(G + (size_t)grow * DF + cbase + 4, acc[i][4], acc[i][5], acc[i][6], acc[i][7]);
  }
}

// ---------------------------------------------------------------------------
// fusedA: [G double-gemm | A2 gemm | combined e+v XCD-partitioned build]
__global__ __launch_bounds__(256) void fusedA(
    const int* __restrict__ ei,
    int* __restrict__ cnt_e, int* __restrict__ cnt_v,
    ushort* __restrict__ lst_e, ushort* __restrict__ lst_v,
    const float* __restrict__ x,
    const float* __restrict__ w1_1, const float* __restrict__ b1_1,
    const float* __restrict__ g1, const float* __restrict__ be1,
    const float* __restrict__ w2_1, const float* __restrict__ Wc,
    float* __restrict__ G, float* __restrict__ A2,
    float* __restrict__ sA, float* __restrict__ qA) {
  __shared__ float as[64 * 132];
  int blk = blockIdx.x;
  if (blk < NB_G1) {
    gemm_tile_double(x, w1_1, b1_1, g1, be1, Wc, G, blk, as);
  } else if (blk < NB_GEMMS) {
    gemm_tile<0, true>(x, NN, w2_1, nullptr, nullptr, nullptr, A2, sA, qA,
                       blk - NB_G1, as);
  } else {
    int b = blk - NB_GEMMS;
    int role = blk & 7;
    int group = b >> 3;
    #pragma unroll
    for (int k = 0; k < 4; ++k) {
      int m = (group * 4 + k) * 256 + threadIdx.x;
      int v = __builtin_nontemporal_load(ei + m);
      int e = __builtin_nontemporal_load(ei + MM + m);
      if ((e & 7) == role) {
        int pe = atomicAdd(&cnt_e[role * (EE >> 3) + (e >> 3)], 1);
        lst_e[e * SE + pe] = (ushort)v;
      }
      if ((v & 7) == role) {
        int pv = atomicAdd(&cnt_v[role * (NN >> 3) + (v >> 3)], 1);
        lst_v[v * SV + pv] = (ushort)e;
      }
    }
  }
}

// ---------------------------------------------------------------------------
// standalone gemm dispatch wrapper (out-gemm)
template <int EPI, bool STATS>
__global__ __launch_bounds__(256) void gemm128(const float* __restrict__ A, int nrows,
                                               const float* __restrict__ W,
                                               const float* __restrict__ bias,
                                               const int* __restrict__ cnt,
                                               const float* __restrict__ xres,
                                               float* __restrict__ C,
                                               float* __restrict__ sOut,
                                               float* __restrict__ qOut) {
  __shared__ float as[64 * 132];
  gemm_tile<EPI, STATS>(A, nrows, W, bias, cnt, xres, C, sOut, qOut,
                        blockIdx.x, as);
}

// ---------------------------------------------------------------------------
// gather1B: B[e] = mean_{v in e} G[v] + bc + b2_1, plus row stats sB,qB.
__global__ __launch_bounds__(256) void gather1B(const float* __restrict__ G,
                                                const int* __restrict__ cnt_e,
                                                const ushort* __restrict__ lst_e,
                                                const float* __restrict__ bcv,
                                                const float* __restrict__ b21,
                                                float* __restrict__ B,
                                                float* __restrict__ sB,
                                                float* __restrict__ qB) {
  int e = blockIdx.x * 4 + (threadIdx.x >> 6);
  int lane = threadIdx.x & 63;
  int g = lane >> 4;
  int l = lane & 15;
  int deg = cnt_e[cidxE(e)];
  const ushort* lst = lst_e + e * SE;
  float4 acc0 = make_float4(0.f, 0.f, 0.f, 0.f);
  float4 acc1 = make_float4(0.f, 0.f, 0.f, 0.f);
  for (int i = g; i < deg; i += 4) {
    int v = lst[i];
    const float* src = G + (size_t)v * DF + l * 8;
    float4 h0 = *reinterpret_cast<const float4*>(src);
    float4 h1 = *reinterpret_cast<const float4*>(src + 4);
    acc0.x += h0.x; acc0.y += h0.y; acc0.z += h0.z; acc0.w += h0.w;
    acc1.x += h1.x; acc1.y += h1.y; acc1.z += h1.z; acc1.w += h1.w;
  }
  #pragma unroll
  for (int mask = 16; mask <= 32; mask <<= 1) {
    acc0.x += __shfl_xor(acc0.x, mask); acc0.y += __shfl_xor(acc0.y, mask);
    acc0.z += __shfl_xor(acc0.z, mask); acc0.w += __shfl_xor(acc0.w, mask);
    acc1.x += __shfl_xor(acc1.x, mask); acc1.y += __shfl_xor(acc1.y, mask);
    acc1.z += __shfl_xor(acc1.z, mask); acc1.w += __shfl_xor(acc1.w, mask);
  }
  if (g == 0) {
    float sc = 1.0f / (float)(deg > 1 ? deg : 1);
    float b[8];
    b[0] = acc0.x * sc + bcv[l * 8 + 0] + b21[l * 8 + 0];
    b[1] = acc0.y * sc + bcv[l * 8 + 1] + b21[l * 8 + 1];
    b[2] = acc0.z * sc + bcv[l * 8 + 2] + b21[l * 8 + 2];
    b[3] = acc0.w * sc + bcv[l * 8 + 3] + b21[l * 8 + 3];
    b[4] = acc1.x * sc + bcv[l * 8 + 4] + b21[l * 8 + 4];
    b[5] = acc1.y * sc + bcv[l * 8 + 5] + b21[l * 8 + 5];
    b[6] = acc1.z * sc + bcv[l * 8 + 6] + b21[l * 8 + 6];
    b[7] = acc1.w * sc + bcv[l * 8 + 7] + b21[l * 8 + 7];
    float* dst = B + (size_t)e * DF + l * 8;
    *reinterpret_cast<float4*>(dst) = make_float4(b[0], b[1], b[2], b[3]);
    *reinterpret_cast<float4*>(dst + 4) = make_float4(b[4], b[5], b[6], b[7]);
    float s = 0.f, q = 0.f;
    #pragma unroll
    for (int j = 0; j < 8; ++j) { s += b[j]; q += b[j] * b[j]; }
    #pragma unroll
    for (int mask = 1; mask <= 8; mask <<= 1) {
      s += __shfl_xor(s, mask, 16);
      q += __shfl_xor(q, mask, 16);
    }
    if (l == 0) { sB[e] = s; qB[e] = q; }
  }
}

// ---------------------------------------------------------------------------
// gather2: Svmean[v] = mean_{e in v} relu(LN(A2[v] + B[e]; g2, be2))
// LN split; 2-way interleave of the per-edge latency chain.
__global__ __launch_bounds__(256) void gather2(const float* __restrict__ A2,
                                               const float* __restrict__ B,
                                               const float* __restrict__ sA,
                                               const float* __restrict__ qA,
                                               const float* __restrict__ sB,
                                               const float* __restrict__ qB,
                                               const int* __restrict__ cnt_v,
                                               const ushort* __restrict__ lst_v,
                                               const float* __restrict__ g2,
                                               const float* __restrict__ be2,
                                               float* __restrict__ Svmean) {
  int v = blockIdx.x * 4 + (threadIdx.x >> 6);
  int lane = threadIdx.x & 63;
  int g = lane >> 4;
  int l = lane & 15;
  const float* ap = A2 + (size_t)v * DF + l * 8;
  float4 a0 = *reinterpret_cast<const float4*>(ap);
  float4 a1 = *reinterpret_cast<const float4*>(ap + 4);
  float4 gv0 = *reinterpret_cast<const float4*>(g2 + l * 8);
  float4 gv1 = *reinterpret_cast<const float4*>(g2 + l * 8 + 4);
  float4 bv0 = *reinterpret_cast<const float4*>(be2 + l * 8);
  float4 bv1 = *reinterpret_cast<const float4*>(be2 + l * 8 + 4);
  float sAv = sA[v];
  float qAv = qA[v];
  int deg = cnt_v[cidxV(v)];
  const ushort* lst = lst_v + v * SV;
  float4 acc0 = make_float4(0.f, 0.f, 0.f, 0.f);
  float4 acc1 = make_float4(0.f, 0.f, 0.f, 0.f);

  int i = g;
  for (; i + 4 < deg; i += 8) {
    int e0 = lst[i];
    int e1 = lst[i + 4];
    const float* bp0 = B + (size_t)e0 * DF + l * 8;
    const float* bp1 = B + (size_t)e1 * DF + l * 8;
    float4 b00 = *reinterpret_cast<const float4*>(bp0);
    float4 b01 = *reinterpret_cast<const float4*>(bp0 + 4);
    float4 b10 = *reinterpret_cast<const float4*>(bp1);
    float4 b11 = *reinterpret_cast<const float4*>(bp1 + 4);
    float d0 = a0.x * b00.x + a0.y * b00.y + a0.z * b00.z + a0.w * b00.w +
               a1.x * b01.x + a1.y * b01.y + a1.z * b01.z + a1.w * b01.w;
    float d1 = a0.x * b10.x + a0.y * b10.y + a0.z * b10.z + a0.w * b10.w +
               a1.x * b11.x + a1.y * b11.y + a1.z * b11.z + a1.w * b11.w;
    d0 += __shfl_xor(d0, 1, 16);  d1 += __shfl_xor(d1, 1, 16);
    d0 += __shfl_xor(d0, 2, 16);  d1 += __shfl_xor(d1, 2, 16);
    d0 += __shfl_xor(d0, 4, 16);  d1 += __shfl_xor(d1, 4, 16);
    d0 += __shfl_xor(d0, 8, 16);  d1 += __shfl_xor(d1, 8, 16);
    float s0 = sAv + sB[e0], s1 = sAv + sB[e1];
    float q0 = qAv + qB[e0] + 2.0f * d0, q1 = qAv + qB[e1] + 2.0f * d1;
    float mean0 = s0 * (1.0f / 128.0f), mean1 = s1 * (1.0f / 128.0f);
    float var0 = q0 * (1.0f / 128.0f) - mean0 * mean0;
    float var1 = q1 * (1.0f / 128.0f) - mean1 * mean1;
    float rs0 = rsqrtf(var0 + EPSF), rs1 = rsqrtf(var1 + EPSF);
    float mrs0 = mean0 * rs0, mrs1 = mean1 * rs1;
    float t;
    t = (a0.x + b00.x) * rs0 - mrs0; acc0.x += fmaxf(t * gv0.x + bv0.x, 0.f);
    t = (a0.y + b00.y) * rs0 - mrs0; acc0.y += fmaxf(t * gv0.y + bv0.y, 0.f);
    t = (a0.z + b00.z) * rs0 - mrs0; acc0.z += fmaxf(t * gv0.z + bv0.z, 0.f);
    t = (a0.w + b00.w) * rs0 - mrs0; acc0.w += fmaxf(t * gv0.w + bv0.w, 0.f);
    t = (a1.x + b01.x) * rs0 - mrs0; acc1.x += fmaxf(t * gv1.x + bv1.x, 0.f);
    t = (a1.y + b01.y) * rs0 - mrs0; acc1.y += fmaxf(t * gv1.y + bv1.y, 0.f);
    t = (a1.z + b01.z) * rs0 - mrs0; acc1.z += fmaxf(t * gv1.z + bv1.z, 0.f);
    t = (a1.w + b01.w) * rs0 - mrs0; acc1.w += fmaxf(t * gv1.w + bv1.w, 0.f);
    t = (a0.x + b10.x) * rs1 - mrs1; acc0.x += fmaxf(t * gv0.x + bv0.x, 0.f);
    t = (a0.y + b10.y) * rs1 - mrs1; acc0.y += fmaxf(t * gv0.y + bv0.y, 0.f);
    t = (a0.z + b10.z) * rs1 - mrs1; acc0.z += fmaxf(t * gv0.z + bv0.z, 0.f);
    t = (a0.w + b10.w) * rs1 - mrs1; acc0.w += fmaxf(t * gv0.w + bv0.w, 0.f);
    t = (a1.x + b11.x) * rs1 - mrs1; acc1.x += fmaxf(t * gv1.x + bv1.x, 0.f);
    t = (a1.y + b11.y) * rs1 - mrs1; acc1.y += fmaxf(t * gv1.y + bv1.y, 0.f);
    t = (a1.z + b11.z) * rs1 - mrs1; acc1.z += fmaxf(t * gv1.z + bv1.z, 0.f);
    t = (a1.w + b11.w) * rs1 - mrs1; acc1.w += fmaxf(t * gv1.w + bv1.w, 0.f);
  }
  if (i < deg) {
    int e = lst[i];
    const float* bp = B + (size_t)e * DF + l * 8;
    float4 b0 = *reinterpret_cast<const float4*>(bp);
    float4 b1 = *reinterpret_cast<const float4*>(bp + 4);
    float d = a0.x * b0.x + a0.y * b0.y + a0.z * b0.z + a0.w * b0.w +
              a1.x * b1.x + a1.y * b1.y + a1.z * b1.z + a1.w * b1.w;
    d += __shfl_xor(d, 1, 16);
    d += __shfl_xor(d, 2, 16);
    d += __shfl_xor(d, 4, 16);
    d += __shfl_xor(d, 8, 16);
    float s = sAv + sB[e];
    float q = qAv + qB[e] + 2.0f * d;
    float mean = s * (1.0f / 128.0f);
    float var = q * (1.0f / 128.0f) - mean * mean;
    float rs = rsqrtf(var + EPSF);
    float mrs = mean * rs;
    float t;
    t = (a0.x + b0.x) * rs - mrs; acc0.x += fmaxf(t * gv0.x + bv0.x, 0.f);
    t = (a0.y + b0.y) * rs - mrs; acc0.y += fmaxf(t * gv0.y + bv0.y, 0.f);
    t = (a0.z + b0.z) * rs - mrs; acc0.z += fmaxf(t * gv0.z + bv0.z, 0.f);
    t = (a0.w + b0.w) * rs - mrs; acc0.w += fmaxf(t * gv0.w + bv0.w, 0.f);
    t = (a1.x + b1.x) * rs - mrs; acc1.x += fmaxf(t * gv1.x + bv1.x, 0.f);
    t = (a1.y + b1.y) * rs - mrs; acc1.y += fmaxf(t * gv1.y + bv1.y, 0.f);
    t = (a1.z + b1.z) * rs - mrs; acc1.z += fmaxf(t * gv1.z + bv1.z, 0.f);
    t = (a1.w + b1.w) * rs - mrs; acc1.w += fmaxf(t * gv1.w + bv1.w, 0.f);
  }

  #pragma unroll
  for (int mask = 16; mask <= 32; mask <<= 1) {
    acc0.x += __shfl_xor(acc0.x, mask); acc0.y += __shfl_xor(acc0.y, mask);
    acc0.z += __shfl_xor(acc0.z, mask); acc0.w += __shfl_xor(acc0.w, mask);
    acc1.x += __shfl_xor(acc1.x, mask); acc1.y += __shfl_xor(acc1.y, mask);
    acc1.z += __shfl_xor(acc1.z, mask); acc1.w += __shfl_xor(acc1.w, mask);
  }
  if (g == 0) {
    float sc = 1.0f / (float)(deg > 1 ? deg : 1);
    float* dst = Svmean + (size_t)v * DF + l * 8;
    *reinterpret_cast<float4*>(dst) =
        make_float4(acc0.x * sc, acc0.y * sc, acc0.z * sc, acc0.w * sc);
    *reinterpret_cast<float4*>(dst + 4) =
        make_float4(acc1.x * sc, acc1.y * sc, acc1.z * sc, acc1.w * sc);
  }
}

// ---------------------------------------------------------------------------
extern "C" void kernel_launch(void* const* d_in, const int* in_sizes, int n_in,
                              void* d_out, int out_size, void* d_ws, size_t ws_size,
                              hipStream_t stream) {
  const float* x    = (const float*)d_in[0];
  const float* w1_1 = (const float*)d_in[1];
  const float* b1_1 = (const float*)d_in[2];
  const float* g1   = (const float*)d_in[3];
  const float* be1  = (const float*)d_in[4];
  const float* w1_2 = (const float*)d_in[5];
  const float* b1_2 = (const float*)d_in[6];
  const float* w2_1 = (const float*)d_in[7];
  const float* b2_1 = (const float*)d_in[8];
  const float* g2   = (const float*)d_in[9];
  const float* be2  = (const float*)d_in[10];
  const float* w2_2 = (const float*)d_in[11];
  const float* b2_2 = (const float*)d_in[12];
  const int* ei     = (const int*)d_in[13];
  float* out = (float*)d_out;

  float* ws = (float*)d_ws;
  float* bufN1 = ws;                    // N*D: G, then Svmean
  float* bufN2 = ws + 5120000;          // N*D: A2
  float* bufE  = ws + 10240000;         // E*D: B
  float* Wc    = ws + 12800000;         // 128*128
  float* bc    = ws + 12816384;         // 128
  float* sA    = ws + 12816512;         // N
  float* qA    = ws + 12856512;         // N
  float* sB    = ws + 12896512;         // E
  float* qB    = ws + 12916512;         // E
  int*   ints  = (int*)(ws + 12936512);
  int* cnt_e  = ints;                   // E  role-remapped (zeroed by prek)
  int* cnt_v  = ints + 20000;           // N  role-remapped (zeroed by prek)
  ushort* lst_e = (ushort*)(ints + 60000);            // EE*SE ushorts
  ushort* lst_v = (ushort*)(ints + 60000 + 960000);   // NN*SV ushorts

  // zero cnt + combo (Wc, bc)
  prek<<<300, 256, 0, stream>>>(cnt_e, w1_2, b1_2, w2_1, Wc, bc);

  // fusedA: G = relu(LN(x@w1_1+b1_1))@Wc || A2 = x@w2_1_top (+stats) || e+v build
  fusedA<<<NB_GEMMS + NB_BUILD, 256, 0, stream>>>(
      ei, cnt_e, cnt_v, lst_e, lst_v, x, w1_1, b1_1, g1, be1, w2_1, Wc,
      bufN1, bufN2, sA, qA);

  // B[e] = mean of G rows + bc + b2_1, with row stats
  gather1B<<<EE / 4, 256, 0, stream>>>(bufN1, cnt_e, lst_e, bc, b2_1,
                                       bufE, sB, qB);

  // Svmean[v] = mean of relu(LN(A2[v] + B[e]))  (into bufN1; G dead)
  gather2<<<NN / 4, 256, 0, stream>>>(bufN2, bufE, sA, qA, sB, qB,
                                      cnt_v, lst_v, g2, be2, bufN1);

  // out = 0.9*(Svmean@w2_2 + b2_2) + 0.1*x   (cnt_v==0 -> 0.1*x)
  gemm128<2, false><<<(NN + 63) / 64, 256, 0, stream>>>(
      bufN1, NN, w2_2, b2_2, cnt_v, x, out, nullptr, nullptr);
}